// Round 5
// baseline (254.886 us; speedup 1.0000x reference)
//
#include <hip/hip_runtime.h>

typedef unsigned short u16;

// bf16 used ONLY for the internal x0 workspace (inputs/outputs are fp32)
__device__ __forceinline__ float us2f(u16 u){
  unsigned int x = ((unsigned int)u) << 16;
  return __uint_as_float(x);
}
__device__ __forceinline__ u16 f2us(float f){
  unsigned int u = __float_as_uint(f);
  unsigned int r = (u + 0x7fffu + ((u >> 16) & 1u)) >> 16;
  return (u16)r;
}
__device__ __forceinline__ float wredMax(float v){
  #pragma unroll
  for (int o = 32; o > 0; o >>= 1) v = fmaxf(v, __shfl_xor(v, o, 64));
  return v;
}
__device__ __forceinline__ float wredSum(float v){
  #pragma unroll
  for (int o = 32; o > 0; o >>= 1) v += __shfl_xor(v, o, 64);
  return v;
}
// butterfly sum across the 32-lane subgroup (all lanes get the total)
__device__ __forceinline__ float g32Sum(float v){
  #pragma unroll
  for (int o = 16; o > 0; o >>= 1) v += __shfl_xor(v, o, 32);
  return v;
}
// butterfly sum across 8-lane subgroup
__device__ __forceinline__ float g8Sum(float v){
  #pragma unroll
  for (int o = 4; o > 0; o >>= 1) v += __shfl_xor(v, o, 32);
  return v;
}

#define ACAP 128  // adjacency capacity per row (Binom(2000,.02): >128 is ~14 sigma)

// ---------------- K0: CSR adjacency (shared by both GAT layers) ----------------
__global__ __launch_bounds__(256) void k_adj(
    const float* __restrict__ sg, u16* __restrict__ adj, int* __restrict__ cnt)
{
  __shared__ int c_s;
  const int t = threadIdx.x;
  const int bi = blockIdx.x;
  const int b = bi / 2000;
  const int i = bi - b * 2000;
  if (t == 0) c_s = 0;
  __syncthreads();
  const float* row = sg + (size_t)bi * 2000;
  for (int j = t; j < 2000; j += 256)
    if (row[j] > 0.f || j == i){
      int p = atomicAdd(&c_s, 1);
      if (p < ACAP) adj[(size_t)bi * ACAP + p] = (u16)j;
    }
  __syncthreads();
  if (t == 0) cnt[bi] = min(c_s, ACAP);
}

// ---------------- K1: fused  h = relu(LN(x@W_in+b_in));  x0=h@W0;  es/ed ----------------
// 2000 blocks x 128 thr; 4 rows/block. Thread t: row r=t>>5, cols c0=(t&31)*4.
__global__ __launch_bounds__(128) void k_inln_gat0(
    const float* __restrict__ xA, const float* __restrict__ Win,
    const float* __restrict__ bin, const float* __restrict__ lng,
    const float* __restrict__ lnb, const float* __restrict__ W0,
    const float* __restrict__ as0, const float* __restrict__ ad0,
    float* __restrict__ h, u16* __restrict__ x0,
    float* __restrict__ es, float* __restrict__ ed)
{
  __shared__ float xs[4][160];     // K=158 padded to 160 (16B-aligned rows)
  __shared__ float tile[4][128];   // h tile (post-LN/ReLU)
  const int t = threadIdx.x;
  const int row0 = blockIdx.x * 4;
  const int b = row0 / 2000;
  const int n0 = row0 - b * 2000;
  const size_t xbase = (((size_t)b * 8 + 7) * 2000 + n0) * 158;

  // stage x rows, zero-pad k=158,159
  for (int idx = t; idx < 4 * 160; idx += 128){
    int r = idx / 160, k = idx - r * 160;
    xs[r][k] = (k < 158) ? xA[xbase + (size_t)r * 158 + k] : 0.f;
  }
  __syncthreads();

  const int r  = t >> 5;
  const int c0 = (t & 31) * 4;

  // GEMM1: acc = x_row @ W_in[:, c0..c0+3]
  float acc0 = 0.f, acc1 = 0.f, acc2 = 0.f, acc3 = 0.f;
  for (int k0 = 0; k0 < 160; k0 += 4){
    float4 a = *(const float4*)&xs[r][k0];
    #pragma unroll
    for (int kk = 0; kk < 4; kk++){
      int k = k0 + kk;
      if (k < 158){
        float4 w = *(const float4*)&Win[(size_t)k * 128 + c0];
        float av = ((const float*)&a)[kk];
        acc0 = fmaf(av, w.x, acc0); acc1 = fmaf(av, w.y, acc1);
        acc2 = fmaf(av, w.z, acc2); acc3 = fmaf(av, w.w, acc3);
      }
    }
  }
  {
    float4 bi = *(const float4*)&bin[c0];
    acc0 += bi.x; acc1 += bi.y; acc2 += bi.z; acc3 += bi.w;
  }

  // LayerNorm across the 32-lane group (row = 128 cols)
  float s  = g32Sum(acc0 + acc1 + acc2 + acc3);
  float sq = g32Sum(acc0*acc0 + acc1*acc1 + acc2*acc2 + acc3*acc3);
  float mu  = s * (1.f / 128.f);
  float var = sq * (1.f / 128.f) - mu * mu;
  float inv = rsqrtf(var + 1e-5f);
  float4 g  = *(const float4*)&lng[c0];
  float4 be = *(const float4*)&lnb[c0];
  float v0 = fmaxf((acc0 - mu) * inv * g.x + be.x, 0.f);
  float v1 = fmaxf((acc1 - mu) * inv * g.y + be.y, 0.f);
  float v2 = fmaxf((acc2 - mu) * inv * g.z + be.z, 0.f);
  float v3 = fmaxf((acc3 - mu) * inv * g.w + be.w, 0.f);
  tile[r][c0] = v0; tile[r][c0+1] = v1; tile[r][c0+2] = v2; tile[r][c0+3] = v3;
  *(float4*)&h[(size_t)(row0 + r) * 128 + c0] = make_float4(v0, v1, v2, v3);
  __syncthreads();

  // GEMM2: x0_row = h_row @ W0[:, c0..c0+3]
  acc0 = acc1 = acc2 = acc3 = 0.f;
  for (int k0 = 0; k0 < 128; k0 += 4){
    float4 a = *(const float4*)&tile[r][k0];
    #pragma unroll
    for (int kk = 0; kk < 4; kk++){
      float4 w = *(const float4*)&W0[(size_t)(k0 + kk) * 128 + c0];
      float av = ((const float*)&a)[kk];
      acc0 = fmaf(av, w.x, acc0); acc1 = fmaf(av, w.y, acc1);
      acc2 = fmaf(av, w.z, acc2); acc3 = fmaf(av, w.w, acc3);
    }
  }
  {
    ushort4 o;
    o.x = f2us(acc0); o.y = f2us(acc1); o.z = f2us(acc2); o.w = f2us(acc3);
    *(ushort4*)(x0 + (size_t)(row0 + r) * 128 + c0) = o;
  }

  // es/ed: per (row, head) dot; head hh = (t&31)>>3 owns cols hh*32..hh*32+31
  {
    float4 av = *(const float4*)&as0[c0];
    float4 dv = *(const float4*)&ad0[c0];
    float ps = acc0*av.x + acc1*av.y + acc2*av.z + acc3*av.w;
    float pd = acc0*dv.x + acc1*dv.y + acc2*dv.z + acc3*dv.w;
    ps = g8Sum(ps); pd = g8Sum(pd);
    int hh = (t & 31) >> 3;
    if (((t & 31) & 7) == 0){
      es[(size_t)(row0 + r) * 4 + hh] = ps;
      ed[(size_t)(row0 + r) * 4 + hh] = pd;
    }
  }
}

// ---------------- K2: layer-1 projection  x1 = h @ W1 ; es/ed ----------------
__global__ __launch_bounds__(128) void k_gat_pre(
    const float* __restrict__ hin, const float* __restrict__ W,
    const float* __restrict__ asv, const float* __restrict__ adv,
    u16* __restrict__ x0, float* __restrict__ es, float* __restrict__ ed)
{
  __shared__ float xs[4][128];
  const int t = threadIdx.x;
  const int row0 = blockIdx.x * 4;
  const int r  = t >> 5;
  const int c0 = (t & 31) * 4;

  *(float4*)&xs[r][c0] = *(const float4*)&hin[(size_t)(row0 + r) * 128 + c0];
  __syncthreads();

  float acc0 = 0.f, acc1 = 0.f, acc2 = 0.f, acc3 = 0.f;
  for (int k0 = 0; k0 < 128; k0 += 4){
    float4 a = *(const float4*)&xs[r][k0];
    #pragma unroll
    for (int kk = 0; kk < 4; kk++){
      float4 w = *(const float4*)&W[(size_t)(k0 + kk) * 128 + c0];
      float av = ((const float*)&a)[kk];
      acc0 = fmaf(av, w.x, acc0); acc1 = fmaf(av, w.y, acc1);
      acc2 = fmaf(av, w.z, acc2); acc3 = fmaf(av, w.w, acc3);
    }
  }
  {
    ushort4 o;
    o.x = f2us(acc0); o.y = f2us(acc1); o.z = f2us(acc2); o.w = f2us(acc3);
    *(ushort4*)(x0 + (size_t)(row0 + r) * 128 + c0) = o;
  }
  {
    float4 av = *(const float4*)&asv[c0];
    float4 dv = *(const float4*)&adv[c0];
    float ps = acc0*av.x + acc1*av.y + acc2*av.z + acc3*av.w;
    float pd = acc0*dv.x + acc1*dv.y + acc2*dv.z + acc3*dv.w;
    ps = g8Sum(ps); pd = g8Sum(pd);
    int hh = (t & 31) >> 3;
    if (((t & 31) & 7) == 0){
      es[(size_t)(row0 + r) * 4 + hh] = ps;
      ed[(size_t)(row0 + r) * 4 + hh] = pd;
    }
  }
}

// ---------------- K3: sparse masked-softmax attention ----------------
// LAYER 0: h[row] += elu(out + bias0)             (concat heads)
// LAYER 1: fused output: out = (mean_h + bias1) @ W_out + b_out  (fp32 store)
template<int LAYER>
__global__ __launch_bounds__(128) void k_attn(
    const u16* __restrict__ adj, const int* __restrict__ cnt,
    const u16* __restrict__ x0,
    const float* __restrict__ es, const float* __restrict__ ed,
    const float* __restrict__ bias, float* __restrict__ hio,
    const float* __restrict__ Wout, const float* __restrict__ bout,
    float* __restrict__ outv)
{
  __shared__ int idx_s[ACAP];
  __shared__ float sc[4][ACAP];
  __shared__ float red[2][4];
  __shared__ float Msh[4], Ssh[4];
  __shared__ float r128[128];
  __shared__ float mrow[32];
  const int t = threadIdx.x;
  const int bi = blockIdx.x;        // b*2000 + i
  const int b = bi / 2000;

  const int m = min(cnt[bi], ACAP);  // >=1 (self loop)

  int j = 0;
  if (t < m){ j = (int)adj[(size_t)bi * ACAP + t]; idx_s[t] = j; }

  float4 edv = *(const float4*)&ed[(size_t)bi * 4];
  float s0 = -1e30f, s1 = -1e30f, s2 = -1e30f, s3 = -1e30f;
  if (t < m){
    float4 esv = *(const float4*)&es[((size_t)b * 2000 + j) * 4];
    s0 = edv.x + esv.x; s0 = s0 > 0.f ? s0 : 0.2f * s0;
    s1 = edv.y + esv.y; s1 = s1 > 0.f ? s1 : 0.2f * s1;
    s2 = edv.z + esv.z; s2 = s2 > 0.f ? s2 : 0.2f * s2;
    s3 = edv.w + esv.w; s3 = s3 > 0.f ? s3 : 0.2f * s3;
  }
  float m0 = wredMax(s0), m1 = wredMax(s1), m2 = wredMax(s2), m3 = wredMax(s3);
  if ((t & 63) == 0){ int w = t >> 6; red[w][0] = m0; red[w][1] = m1; red[w][2] = m2; red[w][3] = m3; }
  __syncthreads();
  if (t < 4) Msh[t] = fmaxf(red[0][t], red[1][t]);
  __syncthreads();

  float M0 = Msh[0], M1 = Msh[1], M2 = Msh[2], M3 = Msh[3];
  float p0 = (t < m) ? __expf(s0 - M0) : 0.f;
  float p1 = (t < m) ? __expf(s1 - M1) : 0.f;
  float p2 = (t < m) ? __expf(s2 - M2) : 0.f;
  float p3 = (t < m) ? __expf(s3 - M3) : 0.f;
  sc[0][t] = p0; sc[1][t] = p1; sc[2][t] = p2; sc[3][t] = p3;
  float q0 = wredSum(p0), q1 = wredSum(p1), q2 = wredSum(p2), q3 = wredSum(p3);
  if ((t & 63) == 0){ int w = t >> 6; red[w][0] = q0; red[w][1] = q1; red[w][2] = q2; red[w][3] = q3; }
  __syncthreads();
  if (t < 4) Ssh[t] = red[0][t] + red[1][t];
  __syncthreads();

  // PV gather; thread t owns (head t>>5, chan t&31) == x0 col t
  const int hh = t >> 5;
  float acc = 0.f;
  const u16* x0b = x0 + (size_t)b * 2000 * 128 + t;
  #pragma unroll 8
  for (int e = 0; e < m; e++){
    int j2 = idx_s[e];
    acc = fmaf(sc[hh][e], us2f(x0b[(size_t)j2 * 128]), acc);
  }
  acc /= Ssh[hh];

  if (LAYER == 0){
    float v = acc + bias[t];
    v = v > 0.f ? v : (__expf(v) - 1.f);          // elu
    hio[(size_t)bi * 128 + t] += v;               // residual
  } else {
    r128[t] = acc;
    __syncthreads();
    if (t < 32)
      mrow[t] = (r128[t] + r128[t + 32] + r128[t + 64] + r128[t + 96]) * 0.25f + bias[t];
    __syncthreads();
    float o = bout[t];
    #pragma unroll
    for (int k = 0; k < 32; k++) o = fmaf(mrow[k], Wout[(size_t)k * 128 + t], o);
    outv[(size_t)bi * 128 + t] = o;
  }
}

extern "C" void kernel_launch(void* const* d_in, const int* in_sizes, int n_in,
                              void* d_out, int out_size, void* d_ws, size_t ws_size,
                              hipStream_t stream) {
  const float* xA   = (const float*)d_in[0];
  const float* sg   = (const float*)d_in[1];
  const float* Win  = (const float*)d_in[2];
  const float* bin  = (const float*)d_in[3];
  const float* lng  = (const float*)d_in[4];
  const float* lnb  = (const float*)d_in[5];
  const float* W0   = (const float*)d_in[6];
  const float* as0  = (const float*)d_in[7];
  const float* ad0  = (const float*)d_in[8];
  const float* b0   = (const float*)d_in[9];
  const float* W1   = (const float*)d_in[10];
  const float* as1  = (const float*)d_in[11];
  const float* ad1  = (const float*)d_in[12];
  const float* b1   = (const float*)d_in[13];
  const float* Wout = (const float*)d_in[14];
  const float* bout = (const float*)d_in[15];

  char* ws = (char*)d_ws;
  float* h    = (float*)(ws);                    // 8000*128 f32  = 4,096,000 B
  u16*   x0   = (u16*)  (ws + 4096000);          // 8000*128 bf16 = 2,048,000 B
  float* es   = (float*)(ws + 6144000);          // 8000*4 f32    =   128,000 B
  float* ed   = (float*)(ws + 6272000);          // 8000*4 f32    =   128,000 B
  u16*   adj  = (u16*)  (ws + 6400000);          // 8000*128 u16  = 2,048,000 B
  int*   cnt  = (int*)  (ws + 8448000);          // 8000 i32      =    32,000 B

  k_adj       <<<8000, 256, 0, stream>>>(sg, adj, cnt);
  k_inln_gat0 <<<2000, 128, 0, stream>>>(xA, Win, bin, lng, lnb, W0, as0, ad0, h, x0, es, ed);
  k_attn<0>   <<<8000, 128, 0, stream>>>(adj, cnt, x0, es, ed, b0, h, nullptr, nullptr, nullptr);
  k_gat_pre   <<<2000, 128, 0, stream>>>(h, W1, as1, ad1, x0, es, ed);
  k_attn<1>   <<<8000, 128, 0, stream>>>(adj, cnt, x0, es, ed, b1, nullptr, Wout, bout, (float*)d_out);
}

// Round 6
// 212.722 us; speedup vs baseline: 1.1982x; 1.1982x over previous
//
#include <hip/hip_runtime.h>

typedef unsigned short u16;

// bf16 used ONLY for the internal x0 workspace (inputs/outputs are fp32)
__device__ __forceinline__ float us2f(u16 u){
  unsigned int x = ((unsigned int)u) << 16;
  return __uint_as_float(x);
}
__device__ __forceinline__ u16 f2us(float f){
  unsigned int u = __float_as_uint(f);
  unsigned int r = (u + 0x7fffu + ((u >> 16) & 1u)) >> 16;
  return (u16)r;
}
__device__ __forceinline__ float wredSum(float v){
  #pragma unroll
  for (int o = 32; o > 0; o >>= 1) v += __shfl_xor(v, o, 64);
  return v;
}
// butterfly sum across 32-lane subgroup (all lanes get total)
__device__ __forceinline__ float g32Sum(float v){
  #pragma unroll
  for (int o = 16; o > 0; o >>= 1) v += __shfl_xor(v, o, 32);
  return v;
}
// butterfly sum across 8-lane subgroup
__device__ __forceinline__ float g8Sum(float v){
  #pragma unroll
  for (int o = 4; o > 0; o >>= 1) v += __shfl_xor(v, o, 32);
  return v;
}

#define ACAP 128  // adjacency capacity per row (Binom(2000,.02): >128 is ~14 sigma)
#define RB 32     // rows per GEMM block

// ---------------- K0: CSR adjacency (shared by both GAT layers) ----------------
__global__ __launch_bounds__(256) void k_adj(
    const float* __restrict__ sg, u16* __restrict__ adj, int* __restrict__ cnt)
{
  __shared__ int c_s;
  const int t = threadIdx.x;
  const int bi = blockIdx.x;
  const int b = bi / 2000;
  const int i = bi - b * 2000;
  if (t == 0) c_s = 0;
  __syncthreads();
  if (t < 250){                               // 250 threads x 8 floats = 2000
    const float4* row4 = (const float4*)(sg + (size_t)bi * 2000);
    float4 v0 = row4[t * 2], v1 = row4[t * 2 + 1];
    const float vv[8] = { v0.x, v0.y, v0.z, v0.w, v1.x, v1.y, v1.z, v1.w };
    int loc[8], nl = 0;
    const int j0 = t * 8;
    #pragma unroll
    for (int q = 0; q < 8; q++){
      int j = j0 + q;
      if (vv[q] > 0.f || j == i) loc[nl++] = j;
    }
    if (nl){
      int p = atomicAdd(&c_s, nl);
      for (int q = 0; q < nl; q++)
        if (p + q < ACAP) adj[(size_t)bi * ACAP + p + q] = (u16)loc[q];
    }
  }
  __syncthreads();
  if (t == 0) cnt[bi] = min(c_s, ACAP);
}

// ---------------- K1: fused  h = relu(LN(x@W_in+b_in));  x0=h@W0;  es/ed ----------------
// 250 blocks x 256 thr. 32 rows/block. Thread: rows rb=ty*4..+3, cols c0=tx*4..+3.
// W staged through LDS in 8-k tiles, register-staged double buffer.
__global__ __launch_bounds__(256) void k_inln_gat0(
    const float* __restrict__ xA, const float* __restrict__ Win,
    const float* __restrict__ bin, const float* __restrict__ lng,
    const float* __restrict__ lnb, const float* __restrict__ W0,
    const float* __restrict__ as0, const float* __restrict__ ad0,
    float* __restrict__ h, u16* __restrict__ x0,
    float* __restrict__ es, float* __restrict__ ed)
{
  __shared__ float xs[RB][160];       // x tile (K=158 padded); reused as h tile
  __shared__ float Wt[2][8][128];     // double-buffered W k-tile
  const int t = threadIdx.x;
  const int row0 = blockIdx.x * RB;
  const int tx = t & 31, ty = t >> 5;
  const int c0 = tx * 4, rbase = ty * 4;
  const int wk = ty;                  // W staging row (0..7)

  // stage x tile (handles batch boundary per row)
  for (int idx = t; idx < RB * 160; idx += 256){
    int r = idx / 160, k = idx - r * 160;
    int row = row0 + r;
    int b = row / 2000, n = row - b * 2000;
    xs[r][k] = (k < 158) ? xA[(((size_t)b * 8 + 7) * 2000 + n) * 158 + k] : 0.f;
  }
  // stage W tile 0
  *(float4*)&Wt[0][wk][c0] = *(const float4*)&Win[(size_t)wk * 128 + c0];
  __syncthreads();

  float acc[4][4];
  #pragma unroll
  for (int r = 0; r < 4; r++)
    #pragma unroll
    for (int c = 0; c < 4; c++) acc[r][c] = 0.f;

  // ---- GEMM1: K=158 (20 tiles of 8, zero-padded) ----
  const int NT1 = 20;
  for (int tl = 0; tl < NT1; tl++){
    const int cur = tl & 1;
    float4 wreg = make_float4(0.f, 0.f, 0.f, 0.f);
    const bool hn = (tl + 1 < NT1);
    if (hn){
      int k = (tl + 1) * 8 + wk;
      if (k < 158) wreg = *(const float4*)&Win[(size_t)k * 128 + c0];
    }
    const int k0 = tl * 8;
    #pragma unroll
    for (int kh = 0; kh < 2; kh++){
      float4 a[4];
      #pragma unroll
      for (int r = 0; r < 4; r++) a[r] = *(const float4*)&xs[rbase + r][k0 + kh * 4];
      #pragma unroll
      for (int kk = 0; kk < 4; kk++){
        float4 w = *(const float4*)&Wt[cur][kh * 4 + kk][c0];
        #pragma unroll
        for (int r = 0; r < 4; r++){
          float av = ((const float*)&a[r])[kk];
          acc[r][0] = fmaf(av, w.x, acc[r][0]);
          acc[r][1] = fmaf(av, w.y, acc[r][1]);
          acc[r][2] = fmaf(av, w.z, acc[r][2]);
          acc[r][3] = fmaf(av, w.w, acc[r][3]);
        }
      }
    }
    if (hn) *(float4*)&Wt[cur ^ 1][wk][c0] = wreg;
    __syncthreads();
  }

  // + bias; LayerNorm per row (32-lane group owns one row's 128 cols)
  {
    float4 bi = *(const float4*)&bin[c0];
    float4 g  = *(const float4*)&lng[c0];
    float4 be = *(const float4*)&lnb[c0];
    #pragma unroll
    for (int r = 0; r < 4; r++){
      float a0 = acc[r][0] + bi.x, a1 = acc[r][1] + bi.y;
      float a2 = acc[r][2] + bi.z, a3 = acc[r][3] + bi.w;
      float s  = g32Sum(a0 + a1 + a2 + a3);
      float sq = g32Sum(a0*a0 + a1*a1 + a2*a2 + a3*a3);
      float mu  = s * (1.f / 128.f);
      float var = sq * (1.f / 128.f) - mu * mu;
      float inv = rsqrtf(var + 1e-5f);
      float v0 = fmaxf((a0 - mu) * inv * g.x + be.x, 0.f);
      float v1 = fmaxf((a1 - mu) * inv * g.y + be.y, 0.f);
      float v2 = fmaxf((a2 - mu) * inv * g.z + be.z, 0.f);
      float v3 = fmaxf((a3 - mu) * inv * g.w + be.w, 0.f);
      *(float4*)&xs[rbase + r][c0] = make_float4(v0, v1, v2, v3);
      *(float4*)&h[(size_t)(row0 + rbase + r) * 128 + c0] = make_float4(v0, v1, v2, v3);
    }
  }
  // stage W0 tile 0
  *(float4*)&Wt[0][wk][c0] = *(const float4*)&W0[(size_t)wk * 128 + c0];
  __syncthreads();

  // ---- GEMM2: x0 = h @ W0, K=128 (16 tiles) ----
  #pragma unroll
  for (int r = 0; r < 4; r++)
    #pragma unroll
    for (int c = 0; c < 4; c++) acc[r][c] = 0.f;
  const int NT2 = 16;
  for (int tl = 0; tl < NT2; tl++){
    const int cur = tl & 1;
    float4 wreg = make_float4(0.f, 0.f, 0.f, 0.f);
    const bool hn = (tl + 1 < NT2);
    if (hn) wreg = *(const float4*)&W0[(size_t)((tl + 1) * 8 + wk) * 128 + c0];
    const int k0 = tl * 8;
    #pragma unroll
    for (int kh = 0; kh < 2; kh++){
      float4 a[4];
      #pragma unroll
      for (int r = 0; r < 4; r++) a[r] = *(const float4*)&xs[rbase + r][k0 + kh * 4];
      #pragma unroll
      for (int kk = 0; kk < 4; kk++){
        float4 w = *(const float4*)&Wt[cur][kh * 4 + kk][c0];
        #pragma unroll
        for (int r = 0; r < 4; r++){
          float av = ((const float*)&a[r])[kk];
          acc[r][0] = fmaf(av, w.x, acc[r][0]);
          acc[r][1] = fmaf(av, w.y, acc[r][1]);
          acc[r][2] = fmaf(av, w.z, acc[r][2]);
          acc[r][3] = fmaf(av, w.w, acc[r][3]);
        }
      }
    }
    if (hn) *(float4*)&Wt[cur ^ 1][wk][c0] = wreg;
    __syncthreads();
  }

  // write x0 (bf16) + es/ed
  {
    float4 av = *(const float4*)&as0[c0];
    float4 dv = *(const float4*)&ad0[c0];
    const int hh = tx >> 3;
    #pragma unroll
    for (int r = 0; r < 4; r++){
      ushort4 o;
      o.x = f2us(acc[r][0]); o.y = f2us(acc[r][1]);
      o.z = f2us(acc[r][2]); o.w = f2us(acc[r][3]);
      *(ushort4*)(x0 + (size_t)(row0 + rbase + r) * 128 + c0) = o;
      float ps = acc[r][0]*av.x + acc[r][1]*av.y + acc[r][2]*av.z + acc[r][3]*av.w;
      float pd = acc[r][0]*dv.x + acc[r][1]*dv.y + acc[r][2]*dv.z + acc[r][3]*dv.w;
      ps = g8Sum(ps); pd = g8Sum(pd);
      if ((tx & 7) == 0){
        es[(size_t)(row0 + rbase + r) * 4 + hh] = ps;
        ed[(size_t)(row0 + rbase + r) * 4 + hh] = pd;
      }
    }
  }
}

// ---------------- K2: layer-1 projection  x1 = h @ W1 ; es/ed ----------------
__global__ __launch_bounds__(256) void k_gat_pre(
    const float* __restrict__ hin, const float* __restrict__ W,
    const float* __restrict__ asv, const float* __restrict__ adv,
    u16* __restrict__ x0, float* __restrict__ es, float* __restrict__ ed)
{
  __shared__ float xs[RB][128];
  __shared__ float Wt[2][8][128];
  const int t = threadIdx.x;
  const int row0 = blockIdx.x * RB;
  const int tx = t & 31, ty = t >> 5;
  const int c0 = tx * 4, rbase = ty * 4;
  const int wk = ty;

  for (int f = t; f < RB * 32; f += 256){      // 1024 float4s
    int r = f >> 5, cq = (f & 31) * 4;
    *(float4*)&xs[r][cq] = *(const float4*)&hin[(size_t)(row0 + r) * 128 + cq];
  }
  *(float4*)&Wt[0][wk][c0] = *(const float4*)&W[(size_t)wk * 128 + c0];
  __syncthreads();

  float acc[4][4];
  #pragma unroll
  for (int r = 0; r < 4; r++)
    #pragma unroll
    for (int c = 0; c < 4; c++) acc[r][c] = 0.f;

  const int NT = 16;
  for (int tl = 0; tl < NT; tl++){
    const int cur = tl & 1;
    float4 wreg = make_float4(0.f, 0.f, 0.f, 0.f);
    const bool hn = (tl + 1 < NT);
    if (hn) wreg = *(const float4*)&W[(size_t)((tl + 1) * 8 + wk) * 128 + c0];
    const int k0 = tl * 8;
    #pragma unroll
    for (int kh = 0; kh < 2; kh++){
      float4 a[4];
      #pragma unroll
      for (int r = 0; r < 4; r++) a[r] = *(const float4*)&xs[rbase + r][k0 + kh * 4];
      #pragma unroll
      for (int kk = 0; kk < 4; kk++){
        float4 w = *(const float4*)&Wt[cur][kh * 4 + kk][c0];
        #pragma unroll
        for (int r = 0; r < 4; r++){
          float av = ((const float*)&a[r])[kk];
          acc[r][0] = fmaf(av, w.x, acc[r][0]);
          acc[r][1] = fmaf(av, w.y, acc[r][1]);
          acc[r][2] = fmaf(av, w.z, acc[r][2]);
          acc[r][3] = fmaf(av, w.w, acc[r][3]);
        }
      }
    }
    if (hn) *(float4*)&Wt[cur ^ 1][wk][c0] = wreg;
    __syncthreads();
  }

  {
    float4 av = *(const float4*)&asv[c0];
    float4 dv = *(const float4*)&adv[c0];
    const int hh = tx >> 3;
    #pragma unroll
    for (int r = 0; r < 4; r++){
      ushort4 o;
      o.x = f2us(acc[r][0]); o.y = f2us(acc[r][1]);
      o.z = f2us(acc[r][2]); o.w = f2us(acc[r][3]);
      *(ushort4*)(x0 + (size_t)(row0 + rbase + r) * 128 + c0) = o;
      float ps = acc[r][0]*av.x + acc[r][1]*av.y + acc[r][2]*av.z + acc[r][3]*av.w;
      float pd = acc[r][0]*dv.x + acc[r][1]*dv.y + acc[r][2]*dv.z + acc[r][3]*dv.w;
      ps = g8Sum(ps); pd = g8Sum(pd);
      if ((tx & 7) == 0){
        es[(size_t)(row0 + rbase + r) * 4 + hh] = ps;
        ed[(size_t)(row0 + rbase + r) * 4 + hh] = pd;
      }
    }
  }
}

// ---------------- K3: sparse masked-softmax attention ----------------
// Scores are bounded (|s| < ~30) so exp without max-subtraction is safe in fp32.
// LAYER 0: h[row] += elu(out + bias0)             (concat heads)
// LAYER 1: fused output: out = (mean_h + bias1) @ W_out + b_out  (fp32 store)
template<int LAYER>
__global__ __launch_bounds__(128) void k_attn(
    const u16* __restrict__ adj, const int* __restrict__ cnt,
    const u16* __restrict__ x0,
    const float* __restrict__ es, const float* __restrict__ ed,
    const float* __restrict__ bias, float* __restrict__ hio,
    const float* __restrict__ Wout, const float* __restrict__ bout,
    float* __restrict__ outv)
{
  __shared__ int idx_s[ACAP];
  __shared__ float sc[4][ACAP];
  __shared__ float red[2][4];
  __shared__ float Ssh[4];
  __shared__ float r128[128];
  __shared__ float mrow[32];
  const int t = threadIdx.x;
  const int bi = blockIdx.x;        // b*2000 + i
  const int b = bi / 2000;

  const int m = min(cnt[bi], ACAP);  // >=1 (self loop)

  float4 edv = *(const float4*)&ed[(size_t)bi * 4];
  float p0 = 0.f, p1 = 0.f, p2 = 0.f, p3 = 0.f;
  if (t < m){
    int j = (int)adj[(size_t)bi * ACAP + t];
    idx_s[t] = j;
    float4 esv = *(const float4*)&es[((size_t)b * 2000 + j) * 4];
    float s0 = edv.x + esv.x; s0 = s0 > 0.f ? s0 : 0.2f * s0;
    float s1 = edv.y + esv.y; s1 = s1 > 0.f ? s1 : 0.2f * s1;
    float s2 = edv.z + esv.z; s2 = s2 > 0.f ? s2 : 0.2f * s2;
    float s3 = edv.w + esv.w; s3 = s3 > 0.f ? s3 : 0.2f * s3;
    p0 = __expf(s0); p1 = __expf(s1); p2 = __expf(s2); p3 = __expf(s3);
    sc[0][t] = p0; sc[1][t] = p1; sc[2][t] = p2; sc[3][t] = p3;
  }
  float q0 = wredSum(p0), q1 = wredSum(p1), q2 = wredSum(p2), q3 = wredSum(p3);
  if ((t & 63) == 0){ int w = t >> 6; red[w][0] = q0; red[w][1] = q1; red[w][2] = q2; red[w][3] = q3; }
  __syncthreads();
  if (t < 4) Ssh[t] = red[0][t] + red[1][t];
  __syncthreads();

  // PV gather; thread t owns (head t>>5, chan t&31) == x0 col t
  const int hh = t >> 5;
  float acc = 0.f;
  const u16* x0b = x0 + (size_t)b * 2000 * 128 + t;
  #pragma unroll 8
  for (int e = 0; e < m; e++){
    int j2 = idx_s[e];
    acc = fmaf(sc[hh][e], us2f(x0b[(size_t)j2 * 128]), acc);
  }
  acc /= Ssh[hh];

  if (LAYER == 0){
    float v = acc + bias[t];
    v = v > 0.f ? v : (__expf(v) - 1.f);          // elu
    hio[(size_t)bi * 128 + t] += v;               // residual
  } else {
    r128[t] = acc;
    __syncthreads();
    if (t < 32)
      mrow[t] = (r128[t] + r128[t + 32] + r128[t + 64] + r128[t + 96]) * 0.25f + bias[t];
    __syncthreads();
    float o = bout[t];
    #pragma unroll
    for (int k = 0; k < 32; k++) o = fmaf(mrow[k], Wout[(size_t)k * 128 + t], o);
    outv[(size_t)bi * 128 + t] = o;
  }
}

extern "C" void kernel_launch(void* const* d_in, const int* in_sizes, int n_in,
                              void* d_out, int out_size, void* d_ws, size_t ws_size,
                              hipStream_t stream) {
  const float* xA   = (const float*)d_in[0];
  const float* sg   = (const float*)d_in[1];
  const float* Win  = (const float*)d_in[2];
  const float* bin  = (const float*)d_in[3];
  const float* lng  = (const float*)d_in[4];
  const float* lnb  = (const float*)d_in[5];
  const float* W0   = (const float*)d_in[6];
  const float* as0  = (const float*)d_in[7];
  const float* ad0  = (const float*)d_in[8];
  const float* b0   = (const float*)d_in[9];
  const float* W1   = (const float*)d_in[10];
  const float* as1  = (const float*)d_in[11];
  const float* ad1  = (const float*)d_in[12];
  const float* b1   = (const float*)d_in[13];
  const float* Wout = (const float*)d_in[14];
  const float* bout = (const float*)d_in[15];

  char* ws = (char*)d_ws;
  float* h    = (float*)(ws);                    // 8000*128 f32  = 4,096,000 B
  u16*   x0   = (u16*)  (ws + 4096000);          // 8000*128 bf16 = 2,048,000 B
  float* es   = (float*)(ws + 6144000);          // 8000*4 f32    =   128,000 B
  float* ed   = (float*)(ws + 6272000);          // 8000*4 f32    =   128,000 B
  u16*   adj  = (u16*)  (ws + 6400000);          // 8000*128 u16  = 2,048,000 B
  int*   cnt  = (int*)  (ws + 8448000);          // 8000 i32      =    32,000 B

  k_adj       <<<8000, 256, 0, stream>>>(sg, adj, cnt);
  k_inln_gat0 <<<250, 256, 0, stream>>>(xA, Win, bin, lng, lnb, W0, as0, ad0, h, x0, es, ed);
  k_attn<0>   <<<8000, 128, 0, stream>>>(adj, cnt, x0, es, ed, b0, h, nullptr, nullptr, nullptr);
  k_gat_pre   <<<250, 256, 0, stream>>>(h, W1, as1, ad1, x0, es, ed);
  k_attn<1>   <<<8000, 128, 0, stream>>>(adj, cnt, x0, es, ed, b1, nullptr, Wout, bout, (float*)d_out);
}

// Round 7
// 196.145 us; speedup vs baseline: 1.2995x; 1.0845x over previous
//
#include <hip/hip_runtime.h>

typedef unsigned short u16;

// bf16 used ONLY for the internal x0 workspace (inputs/outputs are fp32)
__device__ __forceinline__ float us2f(u16 u){
  unsigned int x = ((unsigned int)u) << 16;
  return __uint_as_float(x);
}
__device__ __forceinline__ u16 f2us(float f){
  unsigned int u = __float_as_uint(f);
  unsigned int r = (u + 0x7fffu + ((u >> 16) & 1u)) >> 16;
  return (u16)r;
}
__device__ __forceinline__ float wredSum(float v){
  #pragma unroll
  for (int o = 32; o > 0; o >>= 1) v += __shfl_xor(v, o, 64);
  return v;
}
// butterfly sum across 32-lane subgroup (all lanes get total)
__device__ __forceinline__ float g32Sum(float v){
  #pragma unroll
  for (int o = 16; o > 0; o >>= 1) v += __shfl_xor(v, o, 32);
  return v;
}
// butterfly sum across 8-lane subgroup
__device__ __forceinline__ float g8Sum(float v){
  #pragma unroll
  for (int o = 4; o > 0; o >>= 1) v += __shfl_xor(v, o, 32);
  return v;
}

#define ACAP 128  // adjacency capacity per row (Binom(2000,.02): >128 is ~14 sigma)
#define RB 16     // rows per GEMM block (500 blocks -> 2 blocks/CU, 16 waves/CU)

// ---------------- K1: fused  h = relu(LN(x@W_in+b_in));  x0=h@W0;  es/ed ----------------
// 500 blocks x 256 thr. 16 rows/block. Thread: rows rbase=ty*2..+1, cols c0=tx*4..+3.
// W staged through LDS in 8-k tiles, register-staged double buffer.
__global__ __launch_bounds__(256) void k_inln_gat0(
    const float* __restrict__ xA, const float* __restrict__ Win,
    const float* __restrict__ bin, const float* __restrict__ lng,
    const float* __restrict__ lnb, const float* __restrict__ W0,
    const float* __restrict__ as0, const float* __restrict__ ad0,
    float* __restrict__ h, u16* __restrict__ x0,
    float* __restrict__ es, float* __restrict__ ed)
{
  __shared__ float xs[RB][160];       // x tile (K=158 padded); reused as h tile
  __shared__ float Wt[2][8][128];     // double-buffered W k-tile
  const int t = threadIdx.x;
  const int row0 = blockIdx.x * RB;   // 2000 % 16 == 0: blocks never cross batch
  const int tx = t & 31, ty = t >> 5;
  const int c0 = tx * 4, rbase = ty * 2;
  const int wk = ty;                  // W staging row (0..7)
  const int b = row0 / 2000;
  const int n0 = row0 - b * 2000;
  const size_t xbase = (((size_t)b * 8 + 7) * 2000 + n0) * 158;

  for (int idx = t; idx < RB * 160; idx += 256){
    int r = idx / 160, k = idx - r * 160;
    xs[r][k] = (k < 158) ? xA[xbase + (size_t)r * 158 + k] : 0.f;
  }
  *(float4*)&Wt[0][wk][c0] = *(const float4*)&Win[(size_t)wk * 128 + c0];
  __syncthreads();

  float acc[2][4];
  #pragma unroll
  for (int r = 0; r < 2; r++)
    #pragma unroll
    for (int c = 0; c < 4; c++) acc[r][c] = 0.f;

  // ---- GEMM1: K=158 (20 tiles of 8, zero-padded) ----
  const int NT1 = 20;
  for (int tl = 0; tl < NT1; tl++){
    const int cur = tl & 1;
    float4 wreg = make_float4(0.f, 0.f, 0.f, 0.f);
    const bool hn = (tl + 1 < NT1);
    if (hn){
      int k = (tl + 1) * 8 + wk;
      if (k < 158) wreg = *(const float4*)&Win[(size_t)k * 128 + c0];
    }
    const int k0 = tl * 8;
    #pragma unroll
    for (int kh = 0; kh < 2; kh++){
      float4 a[2];
      #pragma unroll
      for (int r = 0; r < 2; r++) a[r] = *(const float4*)&xs[rbase + r][k0 + kh * 4];
      #pragma unroll
      for (int kk = 0; kk < 4; kk++){
        float4 w = *(const float4*)&Wt[cur][kh * 4 + kk][c0];
        #pragma unroll
        for (int r = 0; r < 2; r++){
          float av = ((const float*)&a[r])[kk];
          acc[r][0] = fmaf(av, w.x, acc[r][0]);
          acc[r][1] = fmaf(av, w.y, acc[r][1]);
          acc[r][2] = fmaf(av, w.z, acc[r][2]);
          acc[r][3] = fmaf(av, w.w, acc[r][3]);
        }
      }
    }
    if (hn) *(float4*)&Wt[cur ^ 1][wk][c0] = wreg;
    __syncthreads();
  }

  // + bias; LayerNorm per row (32-lane group owns one row's 128 cols)
  {
    float4 bi = *(const float4*)&bin[c0];
    float4 g  = *(const float4*)&lng[c0];
    float4 be = *(const float4*)&lnb[c0];
    #pragma unroll
    for (int r = 0; r < 2; r++){
      float a0 = acc[r][0] + bi.x, a1 = acc[r][1] + bi.y;
      float a2 = acc[r][2] + bi.z, a3 = acc[r][3] + bi.w;
      float s  = g32Sum(a0 + a1 + a2 + a3);
      float sq = g32Sum(a0*a0 + a1*a1 + a2*a2 + a3*a3);
      float mu  = s * (1.f / 128.f);
      float var = sq * (1.f / 128.f) - mu * mu;
      float inv = rsqrtf(var + 1e-5f);
      float v0 = fmaxf((a0 - mu) * inv * g.x + be.x, 0.f);
      float v1 = fmaxf((a1 - mu) * inv * g.y + be.y, 0.f);
      float v2 = fmaxf((a2 - mu) * inv * g.z + be.z, 0.f);
      float v3 = fmaxf((a3 - mu) * inv * g.w + be.w, 0.f);
      *(float4*)&xs[rbase + r][c0] = make_float4(v0, v1, v2, v3);
      *(float4*)&h[(size_t)(row0 + rbase + r) * 128 + c0] = make_float4(v0, v1, v2, v3);
    }
  }
  *(float4*)&Wt[0][wk][c0] = *(const float4*)&W0[(size_t)wk * 128 + c0];
  __syncthreads();

  // ---- GEMM2: x0 = h @ W0, K=128 (16 tiles) ----
  #pragma unroll
  for (int r = 0; r < 2; r++)
    #pragma unroll
    for (int c = 0; c < 4; c++) acc[r][c] = 0.f;
  const int NT2 = 16;
  for (int tl = 0; tl < NT2; tl++){
    const int cur = tl & 1;
    float4 wreg = make_float4(0.f, 0.f, 0.f, 0.f);
    const bool hn = (tl + 1 < NT2);
    if (hn) wreg = *(const float4*)&W0[(size_t)((tl + 1) * 8 + wk) * 128 + c0];
    const int k0 = tl * 8;
    #pragma unroll
    for (int kh = 0; kh < 2; kh++){
      float4 a[2];
      #pragma unroll
      for (int r = 0; r < 2; r++) a[r] = *(const float4*)&xs[rbase + r][k0 + kh * 4];
      #pragma unroll
      for (int kk = 0; kk < 4; kk++){
        float4 w = *(const float4*)&Wt[cur][kh * 4 + kk][c0];
        #pragma unroll
        for (int r = 0; r < 2; r++){
          float av = ((const float*)&a[r])[kk];
          acc[r][0] = fmaf(av, w.x, acc[r][0]);
          acc[r][1] = fmaf(av, w.y, acc[r][1]);
          acc[r][2] = fmaf(av, w.z, acc[r][2]);
          acc[r][3] = fmaf(av, w.w, acc[r][3]);
        }
      }
    }
    if (hn) *(float4*)&Wt[cur ^ 1][wk][c0] = wreg;
    __syncthreads();
  }

  {
    float4 av = *(const float4*)&as0[c0];
    float4 dv = *(const float4*)&ad0[c0];
    const int hh = tx >> 3;
    #pragma unroll
    for (int r = 0; r < 2; r++){
      ushort4 o;
      o.x = f2us(acc[r][0]); o.y = f2us(acc[r][1]);
      o.z = f2us(acc[r][2]); o.w = f2us(acc[r][3]);
      *(ushort4*)(x0 + (size_t)(row0 + rbase + r) * 128 + c0) = o;
      float ps = acc[r][0]*av.x + acc[r][1]*av.y + acc[r][2]*av.z + acc[r][3]*av.w;
      float pd = acc[r][0]*dv.x + acc[r][1]*dv.y + acc[r][2]*dv.z + acc[r][3]*dv.w;
      ps = g8Sum(ps); pd = g8Sum(pd);
      if ((tx & 7) == 0){
        es[(size_t)(row0 + rbase + r) * 4 + hh] = ps;
        ed[(size_t)(row0 + rbase + r) * 4 + hh] = pd;
      }
    }
  }
}

// ---------------- K2: layer-1 projection  x1 = h @ W1 ; es/ed ----------------
__global__ __launch_bounds__(256) void k_gat_pre(
    const float* __restrict__ hin, const float* __restrict__ W,
    const float* __restrict__ asv, const float* __restrict__ adv,
    u16* __restrict__ x0, float* __restrict__ es, float* __restrict__ ed)
{
  __shared__ float xs[RB][128];
  __shared__ float Wt[2][8][128];
  const int t = threadIdx.x;
  const int row0 = blockIdx.x * RB;
  const int tx = t & 31, ty = t >> 5;
  const int c0 = tx * 4, rbase = ty * 2;
  const int wk = ty;

  for (int f = t; f < RB * 32; f += 256){
    int r = f >> 5, cq = (f & 31) * 4;
    *(float4*)&xs[r][cq] = *(const float4*)&hin[(size_t)(row0 + r) * 128 + cq];
  }
  *(float4*)&Wt[0][wk][c0] = *(const float4*)&W[(size_t)wk * 128 + c0];
  __syncthreads();

  float acc[2][4];
  #pragma unroll
  for (int r = 0; r < 2; r++)
    #pragma unroll
    for (int c = 0; c < 4; c++) acc[r][c] = 0.f;

  const int NT = 16;
  for (int tl = 0; tl < NT; tl++){
    const int cur = tl & 1;
    float4 wreg = make_float4(0.f, 0.f, 0.f, 0.f);
    const bool hn = (tl + 1 < NT);
    if (hn) wreg = *(const float4*)&W[(size_t)((tl + 1) * 8 + wk) * 128 + c0];
    const int k0 = tl * 8;
    #pragma unroll
    for (int kh = 0; kh < 2; kh++){
      float4 a[2];
      #pragma unroll
      for (int r = 0; r < 2; r++) a[r] = *(const float4*)&xs[rbase + r][k0 + kh * 4];
      #pragma unroll
      for (int kk = 0; kk < 4; kk++){
        float4 w = *(const float4*)&Wt[cur][kh * 4 + kk][c0];
        #pragma unroll
        for (int r = 0; r < 2; r++){
          float av = ((const float*)&a[r])[kk];
          acc[r][0] = fmaf(av, w.x, acc[r][0]);
          acc[r][1] = fmaf(av, w.y, acc[r][1]);
          acc[r][2] = fmaf(av, w.z, acc[r][2]);
          acc[r][3] = fmaf(av, w.w, acc[r][3]);
        }
      }
    }
    if (hn) *(float4*)&Wt[cur ^ 1][wk][c0] = wreg;
    __syncthreads();
  }

  {
    float4 av = *(const float4*)&asv[c0];
    float4 dv = *(const float4*)&adv[c0];
    const int hh = tx >> 3;
    #pragma unroll
    for (int r = 0; r < 2; r++){
      ushort4 o;
      o.x = f2us(acc[r][0]); o.y = f2us(acc[r][1]);
      o.z = f2us(acc[r][2]); o.w = f2us(acc[r][3]);
      *(ushort4*)(x0 + (size_t)(row0 + rbase + r) * 128 + c0) = o;
      float ps = acc[r][0]*av.x + acc[r][1]*av.y + acc[r][2]*av.z + acc[r][3]*av.w;
      float pd = acc[r][0]*dv.x + acc[r][1]*dv.y + acc[r][2]*dv.z + acc[r][3]*dv.w;
      ps = g8Sum(ps); pd = g8Sum(pd);
      if ((tx & 7) == 0){
        es[(size_t)(row0 + rbase + r) * 4 + hh] = ps;
        ed[(size_t)(row0 + rbase + r) * 4 + hh] = pd;
      }
    }
  }
}

// ---------------- K3: fused sparse attention, wave-per-row (4 rows / 256-thr block) ----
// LAYER 0: scans mask row (builds adj/cnt for layer 1), then h[row] += elu(out+bias0)
// LAYER 1: reads adj/cnt, epilogue out = (mean_h + bias1) @ W_out + b_out
// Scores are bounded (|s| < ~30): exp without max-subtraction is safe in fp32 (validated R6).
template<int LAYER>
__global__ __launch_bounds__(256) void k_attn(
    const float* __restrict__ sg,
    u16* __restrict__ adj, int* __restrict__ cnt,
    const u16* __restrict__ x0,
    const float* __restrict__ es, const float* __restrict__ ed,
    const float* __restrict__ bias, float* __restrict__ hio,
    const float* __restrict__ Wout, const float* __restrict__ bout,
    float* __restrict__ outv)
{
  __shared__ int   idx_s[4][ACAP];
  __shared__ float sc[4][4][132];    // [rowslot][head][edge] — 132 pad: 4 head addrs hit distinct banks
  __shared__ int   cnt_s[4];
  const int t = threadIdx.x;
  const int w = t >> 6;              // wave = row slot
  const int l = t & 63;
  const int bi = blockIdx.x * 4 + w; // global row 0..7999
  const int b = bi / 2000;
  const int i = bi - b * 2000;

  // ---- phase A: adjacency ----
  if (LAYER == 0){
    if (l == 0) cnt_s[w] = 0;        // wave-ordered LDS: init precedes atomics below
    const float4* row4 = (const float4*)(sg + (size_t)bi * 2000);
    #pragma unroll
    for (int q = 0; q < 8; q++){
      int f4 = q * 64 + l;           // 0..511, valid < 500
      if (f4 < 500){
        float4 v = row4[f4];
        int j0 = f4 * 4;
        #pragma unroll
        for (int u = 0; u < 4; u++){
          int j = j0 + u;
          float vv = (&v.x)[u];
          if (vv > 0.f || j == i){
            int p = atomicAdd(&cnt_s[w], 1);
            if (p < ACAP){
              idx_s[w][p] = j;
              adj[(size_t)bi * ACAP + p] = (u16)j;
            }
          }
        }
      }
    }
    if (l == 0) cnt[bi] = min(cnt_s[w], ACAP);
  } else {
    int mg = cnt[bi];
    if (l == 0) cnt_s[w] = mg;
    if (l < mg)      idx_s[w][l]      = (int)adj[(size_t)bi * ACAP + l];
    if (64 + l < mg) idx_s[w][64 + l] = (int)adj[(size_t)bi * ACAP + 64 + l];
  }
  __syncthreads();
  const int m = min(cnt_s[w], ACAP);  // >=1 (self loop)

  // ---- phase B: scores + per-head softmax denominators (pure wave ops) ----
  float4 edv = *(const float4*)&ed[(size_t)bi * 4];
  float q0 = 0.f, q1 = 0.f, q2 = 0.f, q3 = 0.f;
  #pragma unroll
  for (int rep = 0; rep < 2; rep++){
    int e = rep * 64 + l;
    if (e < m){
      int j = idx_s[w][e];
      float4 esv = *(const float4*)&es[((size_t)b * 2000 + j) * 4];
      float s0 = edv.x + esv.x; s0 = s0 > 0.f ? s0 : 0.2f * s0;
      float s1 = edv.y + esv.y; s1 = s1 > 0.f ? s1 : 0.2f * s1;
      float s2 = edv.z + esv.z; s2 = s2 > 0.f ? s2 : 0.2f * s2;
      float s3 = edv.w + esv.w; s3 = s3 > 0.f ? s3 : 0.2f * s3;
      float p0 = __expf(s0), p1 = __expf(s1), p2 = __expf(s2), p3 = __expf(s3);
      sc[w][0][e] = p0; sc[w][1][e] = p1; sc[w][2][e] = p2; sc[w][3][e] = p3;
      q0 += p0; q1 += p1; q2 += p2; q3 += p3;
    }
  }
  q0 = wredSum(q0); q1 = wredSum(q1); q2 = wredSum(q2); q3 = wredSum(q3);
  __syncthreads();   // sc visible (also orders across-phase LDS for the compiler)

  // ---- phase C: PV gather; lane l owns cols 2l, 2l+1 (same head hh = l>>4) ----
  const int hh = l >> 4;
  float qh = hh < 2 ? (hh == 0 ? q0 : q1) : (hh == 2 ? q2 : q3);
  float inv = 1.f / qh;
  float a0 = 0.f, a1 = 0.f;
  const u16* x0b = x0 + (size_t)b * 2000 * 128 + 2 * l;
  #pragma unroll 8
  for (int e = 0; e < m; e++){
    float p = sc[w][hh][e];
    int j = idx_s[w][e];
    unsigned int pk = *(const unsigned int*)(x0b + (size_t)j * 128);
    a0 = fmaf(p, us2f((u16)(pk & 0xffffu)), a0);
    a1 = fmaf(p, us2f((u16)(pk >> 16)), a1);
  }
  a0 *= inv; a1 *= inv;

  // ---- phase D: epilogue ----
  if (LAYER == 0){
    float2 bb = *(const float2*)&bias[2 * l];
    float v0 = a0 + bb.x; v0 = v0 > 0.f ? v0 : (__expf(v0) - 1.f);
    float v1 = a1 + bb.y; v1 = v1 > 0.f ? v1 : (__expf(v1) - 1.f);
    float2* hp = (float2*)&hio[(size_t)bi * 128 + 2 * l];
    float2 ho = *hp;
    *hp = make_float2(ho.x + v0, ho.y + v1);
  } else {
    // head mean: col(l)=2l; lanes {l, l^16, l^32, l^48} hold cols {c, c+32, c+64, c+96}
    float s0 = a0 + __shfl_xor(a0, 16); s0 += __shfl_xor(s0, 32);
    float s1 = a1 + __shfl_xor(a1, 16); s1 += __shfl_xor(s1, 32);
    float mv0 = s0 * 0.25f, mv1 = s1 * 0.25f;
    if (l < 16){
      float2 bb = *(const float2*)&bias[2 * l];
      mv0 += bb.x; mv1 += bb.y;
    }
    // out[bi][2l..2l+1] = sum_k mrow[k] * Wout[k][2l..2l+1] + bout
    float2 bo = *(const float2*)&bout[2 * l];
    float o0 = bo.x, o1 = bo.y;
    #pragma unroll
    for (int p = 0; p < 16; p++){
      float mk0 = __shfl(mv0, p);    // mrow[2p]
      float mk1 = __shfl(mv1, p);    // mrow[2p+1]
      float2 w0 = *(const float2*)&Wout[(size_t)(2 * p) * 128 + 2 * l];
      float2 w1 = *(const float2*)&Wout[(size_t)(2 * p + 1) * 128 + 2 * l];
      o0 = fmaf(mk0, w0.x, o0); o1 = fmaf(mk0, w0.y, o1);
      o0 = fmaf(mk1, w1.x, o0); o1 = fmaf(mk1, w1.y, o1);
    }
    *(float2*)&outv[(size_t)bi * 128 + 2 * l] = make_float2(o0, o1);
  }
}

extern "C" void kernel_launch(void* const* d_in, const int* in_sizes, int n_in,
                              void* d_out, int out_size, void* d_ws, size_t ws_size,
                              hipStream_t stream) {
  const float* xA   = (const float*)d_in[0];
  const float* sg   = (const float*)d_in[1];
  const float* Win  = (const float*)d_in[2];
  const float* bin  = (const float*)d_in[3];
  const float* lng  = (const float*)d_in[4];
  const float* lnb  = (const float*)d_in[5];
  const float* W0   = (const float*)d_in[6];
  const float* as0  = (const float*)d_in[7];
  const float* ad0  = (const float*)d_in[8];
  const float* b0   = (const float*)d_in[9];
  const float* W1   = (const float*)d_in[10];
  const float* as1  = (const float*)d_in[11];
  const float* ad1  = (const float*)d_in[12];
  const float* b1   = (const float*)d_in[13];
  const float* Wout = (const float*)d_in[14];
  const float* bout = (const float*)d_in[15];

  char* ws = (char*)d_ws;
  float* h    = (float*)(ws);                    // 8000*128 f32  = 4,096,000 B
  u16*   x0   = (u16*)  (ws + 4096000);          // 8000*128 bf16 = 2,048,000 B
  float* es   = (float*)(ws + 6144000);          // 8000*4 f32    =   128,000 B
  float* ed   = (float*)(ws + 6272000);          // 8000*4 f32    =   128,000 B
  u16*   adj  = (u16*)  (ws + 6400000);          // 8000*128 u16  = 2,048,000 B
  int*   cnt  = (int*)  (ws + 8448000);          // 8000 i32      =    32,000 B

  k_inln_gat0 <<<500, 256, 0, stream>>>(xA, Win, bin, lng, lnb, W0, as0, ad0, h, x0, es, ed);
  k_attn<0>   <<<2000, 256, 0, stream>>>(sg, adj, cnt, x0, es, ed, b0, h, nullptr, nullptr, nullptr);
  k_gat_pre   <<<500, 256, 0, stream>>>(h, W1, as1, ad1, x0, es, ed);
  k_attn<1>   <<<2000, 256, 0, stream>>>(nullptr, adj, cnt, x0, es, ed, b1, nullptr, Wout, bout, (float*)d_out);
}